// Round 3
// baseline (267.009 us; speedup 1.0000x reference)
//
#include <hip/hip_runtime.h>

typedef unsigned short u16t;
typedef short short8 __attribute__((ext_vector_type(8)));
typedef float f32x4 __attribute__((ext_vector_type(4)));

__device__ __forceinline__ u16t f2bf(float f) {
  unsigned int u = __builtin_bit_cast(unsigned int, f);
  u += 0x7FFFu + ((u >> 16) & 1u);   // RNE
  return (u16t)(u >> 16);
}
__device__ __forceinline__ ushort4 cvt4(float4 v) {
  ushort4 r;
  r.x = f2bf(v.x); r.y = f2bf(v.y); r.z = f2bf(v.z); r.w = f2bf(v.w);
  return r;
}
__device__ __forceinline__ short8 pack8(ushort4 a, ushort4 b) {
  short8 r;
  r[0] = (short)a.x; r[1] = (short)a.y; r[2] = (short)a.z; r[3] = (short)a.w;
  r[4] = (short)b.x; r[5] = (short)b.y; r[6] = (short)b.z; r[7] = (short)b.w;
  return r;
}

// w_lds (u16 elements): WX1 @0 (8704), WY1 @8704 (8704), W2C-x @17408 (2x64), W2C-y @17536 (2x64)
#define LDS_WX1 0
#define LDS_WY1 8704
#define LDS_W2C 17408
// f_lds (f32 elements), per-path stride 528: B1 @+0 (128), W2 @+128 (384), B2 @+512 (2)
#define FP_STRIDE 528

__global__ __launch_bounds__(256, 2)
void icb_kernel(const float* __restrict__ g_coords, const float* __restrict__ g_c,
                const float* __restrict__ g_Wx1, const float* __restrict__ g_bx1,
                const float* __restrict__ g_Wx2, const float* __restrict__ g_bx2,
                const float* __restrict__ g_Wy1, const float* __restrict__ g_by1,
                const float* __restrict__ g_Wy2, const float* __restrict__ g_by2,
                float* __restrict__ g_out)
{
  __shared__ __align__(16) u16t  c_lds[256 * 72];   // bf16 c tile, stride 72
  __shared__ __align__(16) u16t  w_lds[17664];      // bf16 W1 both paths + W2 c-cols
  __shared__ __align__(16) float f_lds[1056];       // fp32 b1/W2/b2 both paths
  __shared__ __align__(16) float2 xy_lds[256];

  const int tid  = threadIdx.x;
  const int row0 = blockIdx.x * 256;

  // ---- stage c tile: fp32 -> bf16, coalesced float4 loads ----
  #pragma unroll
  for (int it = 0; it < 16; ++it) {
    int i = it * 256 + tid;           // 4096 float4 chunks (256 rows x 16)
    int r = i >> 4, o = i & 15;
    float4 v = reinterpret_cast<const float4*>(g_c)[(size_t)(row0 + r) * 16 + o];
    *reinterpret_cast<ushort4*>(&c_lds[r * 72 + o * 4]) = cvt4(v);
  }
  // ---- coords (x,y fp32 pair) ----
  xy_lds[tid] = reinterpret_cast<const float2*>(g_coords)[row0 + tid];
  // ---- W1 both paths: 2176 float4 each -> bf16 ----
  for (int i = tid; i < 2176; i += 256) {
    *reinterpret_cast<ushort4*>(&w_lds[LDS_WX1 + i * 4]) =
        cvt4(reinterpret_cast<const float4*>(g_Wx1)[i]);
    *reinterpret_cast<ushort4*>(&w_lds[LDS_WY1 + i * 4]) =
        cvt4(reinterpret_cast<const float4*>(g_Wy1)[i]);
  }
  // ---- W2 c-columns (128..191) -> bf16, both paths ----
  {
    int p = tid >> 7, t = tid & 127, o = t >> 6, k = t & 63;
    const float* W2 = p ? g_Wy2 : g_Wx2;
    w_lds[LDS_W2C + p * 128 + o * 64 + k] = f2bf(W2[o * 192 + 128 + k]);
  }
  // ---- fp32 extras: b1, full W2, b2 per path ----
  {
    float4* f4 = reinterpret_cast<float4*>(f_lds);
    if (tid < 32)                f4[tid]       = reinterpret_cast<const float4*>(g_bx1)[tid];
    if (tid >= 32 && tid < 128)  f4[tid]       = reinterpret_cast<const float4*>(g_Wx2)[tid - 32];   // f_lds[128..511]  (FIXED: was f4[100+tid])
    if (tid >= 128 && tid < 160) f4[4 + tid]   = reinterpret_cast<const float4*>(g_by1)[tid - 128];  // f_lds[528..655]
    if (tid >= 160)              f4[4 + tid]   = reinterpret_cast<const float4*>(g_Wy2)[tid - 160];  // f_lds[656..1039]
    if (tid == 0) { f_lds[512]  = g_bx2[0]; f_lds[513]  = g_bx2[1]; }
    if (tid == 1) { f_lds[FP_STRIDE + 512] = g_by2[0]; f_lds[FP_STRIDE + 513] = g_by2[1]; }
  }
  __syncthreads();
  // ---- waves fully independent from here ----

  const int lane = tid & 63;
  const int wave = tid >> 6;
  const int l15  = lane & 15;
  const int quad = lane >> 4;
  const int wrow = wave * 64;   // 4 M-tiles of 16 rows per wave

  float xold[4], yold[4];
  #pragma unroll
  for (int mt = 0; mt < 4; ++mt) {
    float2 p = xy_lds[wrow + mt * 16 + l15];
    xold[mt] = p.x;  yold[mt] = p.y;
  }

  // A-frags for c (K-perm: k 0..63 = c cols). lane holds c[m=l15][quad*8+j (+32)]
  short8 aC0[4], aC1[4];
  #pragma unroll
  for (int mt = 0; mt < 4; ++mt) {
    const int r = wrow + mt * 16 + l15;
    aC0[mt] = *reinterpret_cast<const short8*>(&c_lds[r * 72 + quad * 8]);
    aC1[mt] = *reinterpret_cast<const short8*>(&c_lds[r * 72 + 32 + quad * 8]);
  }

  const float s1  = 0.121267812518166f;    // 1/sqrt(68)
  const float s2  = 0.0721687836487032f;   // 1/sqrt(192)
  const float SQ2 = 1.41421356237309515f;

  float vin[4], ynew[4], xnew[4], yls[4], xls[4];
  #pragma unroll
  for (int mt = 0; mt < 4; ++mt) vin[mt] = xold[mt];

  #pragma unroll 1
  for (int path = 0; path < 2; ++path) {
    const u16t*  W1  = w_lds + (path ? LDS_WY1 : LDS_WX1);
    const u16t*  W2C = w_lds + LDS_W2C + path * 128;
    const float* F   = f_lds + path * FP_STRIDE;
    const float b20 = F[512], b21 = F[513];

    // sinusoidal A-frag: K-perm k 64..67 = [sin a, sin 2a, cos a, cos 2a]
    short8 aS[4];
    #pragma unroll
    for (int mt = 0; mt < 4; ++mt) {
      short8 f = (short8)0;
      if (quad == 0) {
        float a = vin[mt] * 0.1f;
        float sa, ca;
        __sincosf(a, &sa, &ca);
        float s2a = 2.0f * sa * ca;
        float c2a = 1.0f - 2.0f * sa * sa;
        f[0] = (short)f2bf(sa);  f[1] = (short)f2bf(s2a);
        f[2] = (short)f2bf(ca);  f[3] = (short)f2bf(c2a);
      }
      aS[mt] = f;
    }

    float hp[4][4][2];   // [mt][reg j][out o] layer-2 h-part partials
    #pragma unroll
    for (int mt = 0; mt < 4; ++mt)
      #pragma unroll
      for (int j = 0; j < 4; ++j) { hp[mt][j][0] = 0.f; hp[mt][j][1] = 0.f; }

    #pragma unroll 1
    for (int nt = 0; nt < 8; ++nt) {
      const int n = nt * 16 + l15;
      const u16t* rp = W1 + n * 68;
      // B[k][n]=W1[n][col]; K-perm: k<64 -> col 4+k ; k 64..67 -> col 0..3
      ushort4 q0 = *reinterpret_cast<const ushort4*>(rp + 4  + quad * 8);
      ushort4 q1 = *reinterpret_cast<const ushort4*>(rp + 8  + quad * 8);
      ushort4 q2 = *reinterpret_cast<const ushort4*>(rp + 36 + quad * 8);
      ushort4 q3 = *reinterpret_cast<const ushort4*>(rp + 40 + quad * 8);
      short8 bb0 = pack8(q0, q1);
      short8 bb1 = pack8(q2, q3);
      short8 bs = (short8)0;
      if (quad == 0) {
        ushort4 h = *reinterpret_cast<const ushort4*>(rp);  // cols 0..3
        bs[0] = (short)h.x; bs[1] = (short)h.y; bs[2] = (short)h.z; bs[3] = (short)h.w;
      }
      const float b1v = F[n];
      const float w20 = F[128 + n] * SQ2;          // fold sqrt2 of activation
      const float w21 = F[128 + 192 + n] * SQ2;

      #pragma unroll
      for (int mt = 0; mt < 4; ++mt) {
        f32x4 acc = {0.f, 0.f, 0.f, 0.f};
        acc = __builtin_amdgcn_mfma_f32_16x16x32_bf16(aC0[mt], bb0, acc, 0, 0, 0);
        acc = __builtin_amdgcn_mfma_f32_16x16x32_bf16(aC1[mt], bb1, acc, 0, 0, 0);
        acc = __builtin_amdgcn_mfma_f32_16x16x32_bf16(aS[mt],  bs,  acc, 0, 0, 0);
        #pragma unroll
        for (int j = 0; j < 4; ++j) {
          float v = fmaf(s1, acc[j], b1v);     // scale + bias
          float h = fmaxf(v, 0.2f * v);        // leaky_relu (sqrt2 folded into w2)
          hp[mt][j][0] = fmaf(h, w20, hp[mt][j][0]);
          hp[mt][j][1] = fmaf(h, w21, hp[mt][j][1]);
        }
      }
    }

    // layer-2 c-part via MFMA: B rows = W2 out-rows (cols 128..191), D cols 0/1
    short8 bc0 = (short8)0, bc1 = (short8)0;
    if (l15 < 2) {
      const u16t* r2 = W2C + l15 * 64;
      ushort4 p0 = *reinterpret_cast<const ushort4*>(r2 + quad * 8);
      ushort4 p1 = *reinterpret_cast<const ushort4*>(r2 + 4 + quad * 8);
      ushort4 p2 = *reinterpret_cast<const ushort4*>(r2 + 32 + quad * 8);
      ushort4 p3 = *reinterpret_cast<const ushort4*>(r2 + 36 + quad * 8);
      bc0 = pack8(p0, p1);
      bc1 = pack8(p2, p3);
    }
    f32x4 acc8[4];
    #pragma unroll
    for (int mt = 0; mt < 4; ++mt) {
      f32x4 a = {0.f, 0.f, 0.f, 0.f};
      a = __builtin_amdgcn_mfma_f32_16x16x32_bf16(aC0[mt], bc0, a, 0, 0, 0);
      a = __builtin_amdgcn_mfma_f32_16x16x32_bf16(aC1[mt], bc1, a, 0, 0, 0);
      acc8[mt] = a;
    }

    // butterfly-reduce hp across the 16 lanes of each quad (n cols 0..127)
    #pragma unroll
    for (int mt = 0; mt < 4; ++mt)
      #pragma unroll
      for (int j = 0; j < 4; ++j)
        #pragma unroll
        for (int o = 0; o < 2; ++o) {
          float v = hp[mt][j][o];
          v += __shfl_xor(v, 1);
          v += __shfl_xor(v, 2);
          v += __shfl_xor(v, 4);
          v += __shfl_xor(v, 8);
          hp[mt][j][o] = v;
        }

    const int qsrc = (l15 >> 2) << 4;  // a lane of the quad holding row m=l15
    const int jm   = l15 & 3;
    #pragma unroll
    for (int mt = 0; mt < 4; ++mt) {
      float t0[4], t1[4];
      #pragma unroll
      for (int j = 0; j < 4; ++j) {
        float cp0 = __shfl(acc8[mt][j], (lane & 48));        // D col 0 at l15=0 of my quad
        float cp1 = __shfl(acc8[mt][j], (lane & 48) | 1);    // D col 1
        t0[j] = fmaf(s2, hp[mt][j][0] + cp0, b20);
        t1[j] = fmaf(s2, hp[mt][j][1] + cp1, b21);
      }
      float u0 = __shfl(t0[0], qsrc), u1 = __shfl(t0[1], qsrc),
            u2 = __shfl(t0[2], qsrc), u3 = __shfl(t0[3], qsrc);
      float lsraw = (jm == 0) ? u0 : (jm == 1) ? u1 : (jm == 2) ? u2 : u3;
      float v0 = __shfl(t1[0], qsrc), v1 = __shfl(t1[1], qsrc),
            v2 = __shfl(t1[2], qsrc), v3 = __shfl(t1[3], qsrc);
      float brow = (jm == 0) ? v0 : (jm == 1) ? v1 : (jm == 2) ? v2 : v3;

      float ls = fminf(fmaxf(lsraw, -5.f), 5.f);
      float e  = __expf(ls);
      if (path == 0) {
        yls[mt]  = ls;
        ynew[mt] = fmaf(yold[mt], e, brow);
        vin[mt]  = ynew[mt];         // y-path sinusoidals use updated y
      } else {
        xls[mt]  = ls;
        xnew[mt] = fmaf(xold[mt], e, brow);
      }
    }
  }

  // ---- outputs: warped (x,y) then log_jac, fp32 ----
  if (lane < 16) {
    #pragma unroll
    for (int mt = 0; mt < 4; ++mt) {
      int R = row0 + wrow + mt * 16 + lane;
      float2 pw; pw.x = xnew[mt]; pw.y = ynew[mt];
      reinterpret_cast<float2*>(g_out)[R] = pw;
      g_out[1048576 + R] = xls[mt] + yls[mt];
    }
  }
}

extern "C" void kernel_launch(void* const* d_in, const int* in_sizes, int n_in,
                              void* d_out, int out_size, void* d_ws, size_t ws_size,
                              hipStream_t stream) {
  (void)in_sizes; (void)n_in; (void)out_size; (void)d_ws; (void)ws_size;
  icb_kernel<<<2048, 256, 0, stream>>>(
      (const float*)d_in[0], (const float*)d_in[1],
      (const float*)d_in[2], (const float*)d_in[3],
      (const float*)d_in[4], (const float*)d_in[5],
      (const float*)d_in[6], (const float*)d_in[7],
      (const float*)d_in[8], (const float*)d_in[9],
      (float*)d_out);
}

// Round 4
// 240.842 us; speedup vs baseline: 1.1087x; 1.1087x over previous
//
#include <hip/hip_runtime.h>

typedef unsigned short u16t;
typedef short short8 __attribute__((ext_vector_type(8)));
typedef float f32x4 __attribute__((ext_vector_type(4)));

__device__ __forceinline__ u16t f2bf_rne(float f) {
  unsigned u = __builtin_bit_cast(unsigned, f);
  u += 0x7FFFu + ((u >> 16) & 1u);
  return (u16t)(u >> 16);
}
// pack two fp32 -> bf16 pair (round-half-up: same 0.5-ulp bound as RNE, 5 VALU)
__device__ __forceinline__ unsigned pk2(float a, float b) {
  unsigned ua = __builtin_bit_cast(unsigned, a) + 0x8000u;
  unsigned ub = __builtin_bit_cast(unsigned, b) + 0x8000u;
  return (ua >> 16) | (ub & 0xFFFF0000u);
}
union S8U { short8 s; unsigned w[4]; };
__device__ __forceinline__ short8 pack8f(float4 a, float4 b) {
  S8U u;
  u.w[0] = pk2(a.x, a.y); u.w[1] = pk2(a.z, a.w);
  u.w[2] = pk2(b.x, b.y); u.w[3] = pk2(b.z, b.w);
  return u.s;
}

// d_ws byte offsets (all 16B-aligned)
#define WS_WB  0        // W1 B-frags [p][nt][half][lane] 16B  = 32768 B
#define WS_BS  32768    // sin-col B-frags [p][nt][lane] 16B   = 16384 B
#define WS_FF  49152    // fp32 {b1, w2o0*sq2, w2o1*sq2, 0} [p][nt][lane] = 16384 B
#define WS_BC  65536    // W2 c-col B-frags [p][half][lane] 16B = 4096 B

// ---------------- prep: convert + permute weights into d_ws (one block) ----
__global__ void prep_kernel(const float* __restrict__ Wx1, const float* __restrict__ bx1,
                            const float* __restrict__ Wx2,
                            const float* __restrict__ Wy1, const float* __restrict__ by1,
                            const float* __restrict__ Wy2,
                            char* __restrict__ ws)
{
  const int tid = threadIdx.x;          // 1024 threads: (p, nt, lane)
  const int p = tid >> 9, nt = (tid >> 6) & 7, lane = tid & 63;
  const int l15 = lane & 15, quad = lane >> 4;
  const float* W1 = p ? Wy1 : Wx1;
  const float* B1 = p ? by1 : bx1;
  const float* W2 = p ? Wy2 : Wx2;
  const int n = nt * 16 + l15;
  const float* rp = W1 + n * 68;
  short8 bb0, bb1, bs = (short8)0;
  #pragma unroll
  for (int j = 0; j < 8; ++j) {
    bb0[j] = (short)f2bf_rne(rp[4 + quad * 8 + j]);    // K-perm: k<64 -> col 4+k
    bb1[j] = (short)f2bf_rne(rp[36 + quad * 8 + j]);   // k 32..63 -> col 36+...
  }
  if (quad == 0) {
    #pragma unroll
    for (int j = 0; j < 4; ++j) bs[j] = (short)f2bf_rne(rp[j]);  // k 64..67 -> col 0..3
  }
  short8* wb = (short8*)(ws + WS_WB);
  wb[((p * 8 + nt) * 2 + 0) * 64 + lane] = bb0;
  wb[((p * 8 + nt) * 2 + 1) * 64 + lane] = bb1;
  ((short8*)(ws + WS_BS))[(p * 8 + nt) * 64 + lane] = bs;
  const float SQ2 = 1.41421356237309515f;
  float4 ff;
  ff.x = B1[n]; ff.y = W2[n] * SQ2; ff.z = W2[192 + n] * SQ2; ff.w = 0.f;
  ((float4*)(ws + WS_FF))[(p * 8 + nt) * 64 + lane] = ff;

  if (tid < 256) {   // W2 c-columns (128..191) as B-frags, D cols 0/1 = outputs
    const int p2 = tid >> 7, h = (tid >> 6) & 1, ln = tid & 63;
    const int l2 = ln & 15, q2 = ln >> 4;
    const float* W2b = p2 ? Wy2 : Wx2;
    short8 bc = (short8)0;
    if (l2 < 2) {
      #pragma unroll
      for (int j = 0; j < 8; ++j)
        bc[j] = (short)f2bf_rne(W2b[l2 * 192 + 128 + h * 32 + q2 * 8 + j]);
    }
    ((short8*)(ws + WS_BC))[(p2 * 2 + h) * 64 + ln] = bc;
  }
}

// ---------------- main: zero LDS, 32 rows/wave ----------------------------
__global__ __launch_bounds__(256, 4)
void icb_main(const float* __restrict__ g_coords, const float* __restrict__ g_c,
              const float* __restrict__ g_bx2, const float* __restrict__ g_by2,
              const char* __restrict__ ws, float* __restrict__ g_out)
{
  const int tid  = threadIdx.x;
  const int lane = tid & 63, wave = tid >> 6;
  const int l15  = lane & 15, quad = lane >> 4;
  const int wbase = blockIdx.x * 128 + wave * 32;   // 2 m-tiles of 16 rows

  const short8* wb  = (const short8*)(ws + WS_WB);
  const short8* wbs = (const short8*)(ws + WS_BS);
  const float4* wf  = (const float4*)(ws + WS_FF);
  const short8* wbc = (const short8*)(ws + WS_BC);

  // A-frags for c, straight from global (K-perm: k 0..63 = c cols)
  short8 aC0[2], aC1[2];
  float xold[2], yold[2];
  #pragma unroll
  for (int mt = 0; mt < 2; ++mt) {
    const int r = wbase + mt * 16 + l15;
    const float4* cr = (const float4*)(g_c + (size_t)r * 64);
    float4 a0 = cr[quad * 2],     a1 = cr[quad * 2 + 1];
    float4 a2 = cr[8 + quad * 2], a3 = cr[8 + quad * 2 + 1];
    aC0[mt] = pack8f(a0, a1);
    aC1[mt] = pack8f(a2, a3);
    float2 p = ((const float2*)g_coords)[r];
    xold[mt] = p.x; yold[mt] = p.y;
  }

  const float s1 = 0.121267812518166f;    // 1/sqrt(68)
  const float s2 = 0.0721687836487032f;   // 1/sqrt(192)

  float vin[2], xnew[2], ynew[2], xls[2], yls[2];
  vin[0] = xold[0]; vin[1] = xold[1];

  #pragma unroll 1
  for (int path = 0; path < 2; ++path) {
    const int pb = path * 8;
    const float* b2 = path ? g_by2 : g_bx2;
    const float b20 = b2[0], b21 = b2[1];

    // sinusoidal A-frag: k 64..67 = [sin a, sin 2a, cos a, cos 2a] (quad 0 only)
    short8 aS[2];
    #pragma unroll
    for (int mt = 0; mt < 2; ++mt) {
      short8 f = (short8)0;
      if (quad == 0) {
        float a = vin[mt] * 0.1f;
        float sa, ca;
        __sincosf(a, &sa, &ca);
        float s2a = 2.0f * sa * ca;
        float c2a = 1.0f - 2.0f * sa * sa;
        f[0] = (short)f2bf_rne(sa); f[1] = (short)f2bf_rne(s2a);
        f[2] = (short)f2bf_rne(ca); f[3] = (short)f2bf_rne(c2a);
      }
      aS[mt] = f;
    }

    // layer-2 c-part via MFMA (D cols 0/1 = the two outputs)
    short8 bc0 = wbc[(path * 2 + 0) * 64 + lane];
    short8 bc1 = wbc[(path * 2 + 1) * 64 + lane];
    f32x4 acc8[2];
    #pragma unroll
    for (int mt = 0; mt < 2; ++mt) {
      f32x4 a = {0.f, 0.f, 0.f, 0.f};
      a = __builtin_amdgcn_mfma_f32_16x16x32_bf16(aC0[mt], bc0, a, 0, 0, 0);
      a = __builtin_amdgcn_mfma_f32_16x16x32_bf16(aC1[mt], bc1, a, 0, 0, 0);
      acc8[mt] = a;
    }

    float hp[2][4][2];
    #pragma unroll
    for (int mt = 0; mt < 2; ++mt)
      #pragma unroll
      for (int j = 0; j < 4; ++j) { hp[mt][j][0] = 0.f; hp[mt][j][1] = 0.f; }

    #pragma unroll 2
    for (int nt = 0; nt < 8; ++nt) {
      short8 bb0 = wb[((pb + nt) * 2 + 0) * 64 + lane];
      short8 bb1 = wb[((pb + nt) * 2 + 1) * 64 + lane];
      short8 bs  = wbs[(pb + nt) * 64 + lane];
      float4 ff  = wf[(pb + nt) * 64 + lane];   // {b1, w20*sq2, w21*sq2, 0} at n=nt*16+l15
      #pragma unroll
      for (int mt = 0; mt < 2; ++mt) {
        f32x4 acc = {0.f, 0.f, 0.f, 0.f};
        acc = __builtin_amdgcn_mfma_f32_16x16x32_bf16(aC0[mt], bb0, acc, 0, 0, 0);
        acc = __builtin_amdgcn_mfma_f32_16x16x32_bf16(aC1[mt], bb1, acc, 0, 0, 0);
        acc = __builtin_amdgcn_mfma_f32_16x16x32_bf16(aS[mt],  bs,  acc, 0, 0, 0);
        #pragma unroll
        for (int j = 0; j < 4; ++j) {
          float v = fmaf(s1, acc[j], ff.x);
          float h = fmaxf(v, 0.2f * v);       // leaky_relu (sqrt2 folded into w2)
          hp[mt][j][0] = fmaf(h, ff.y, hp[mt][j][0]);
          hp[mt][j][1] = fmaf(h, ff.z, hp[mt][j][1]);
        }
      }
    }

    // fold c-part into hp before the butterfly (lane l15==o contributes col o)
    #pragma unroll
    for (int mt = 0; mt < 2; ++mt)
      #pragma unroll
      for (int j = 0; j < 4; ++j) {
        hp[mt][j][0] += (l15 == 0) ? acc8[mt][j] : 0.f;
        hp[mt][j][1] += (l15 == 1) ? acc8[mt][j] : 0.f;
      }

    // butterfly-reduce over the 16 lanes of each quad-group
    #pragma unroll
    for (int mt = 0; mt < 2; ++mt)
      #pragma unroll
      for (int j = 0; j < 4; ++j)
        #pragma unroll
        for (int o = 0; o < 2; ++o) {
          float v = hp[mt][j][o];
          v += __shfl_xor(v, 1);
          v += __shfl_xor(v, 2);
          v += __shfl_xor(v, 4);
          v += __shfl_xor(v, 8);
          hp[mt][j][o] = v;
        }

    const int jm = l15 & 3;
    const int src = ((l15 >> 2) << 4) | jm;   // lane in group l15>>2 holding row l15 after select
    #pragma unroll
    for (int mt = 0; mt < 2; ++mt) {
      float t0[4], t1[4];
      #pragma unroll
      for (int j = 0; j < 4; ++j) {
        t0[j] = fmaf(s2, hp[mt][j][0], b20);
        t1[j] = fmaf(s2, hp[mt][j][1], b21);
      }
      float s0 = (jm & 1) ? t0[1] : t0[0], s0b = (jm & 1) ? t0[3] : t0[2];
      s0 = (jm & 2) ? s0b : s0;
      float s1v = (jm & 1) ? t1[1] : t1[0], s1b = (jm & 1) ? t1[3] : t1[2];
      s1v = (jm & 2) ? s1b : s1v;
      float lsraw = __shfl(s0, src);
      float brow  = __shfl(s1v, src);

      float ls = fminf(fmaxf(lsraw, -5.f), 5.f);
      float e  = __expf(ls);
      if (path == 0) {
        yls[mt]  = ls;
        ynew[mt] = fmaf(yold[mt], e, brow);
        vin[mt]  = ynew[mt];          // y-path sinusoidals use updated y
      } else {
        xls[mt]  = ls;
        xnew[mt] = fmaf(xold[mt], e, brow);
      }
    }
  }

  // outputs: warped (x,y) then log_jac, fp32
  if (lane < 16) {
    #pragma unroll
    for (int mt = 0; mt < 2; ++mt) {
      int R = wbase + mt * 16 + lane;
      float2 pw; pw.x = xnew[mt]; pw.y = ynew[mt];
      reinterpret_cast<float2*>(g_out)[R] = pw;
      g_out[1048576 + R] = xls[mt] + yls[mt];
    }
  }
}

extern "C" void kernel_launch(void* const* d_in, const int* in_sizes, int n_in,
                              void* d_out, int out_size, void* d_ws, size_t ws_size,
                              hipStream_t stream) {
  (void)in_sizes; (void)n_in; (void)out_size; (void)ws_size;
  prep_kernel<<<1, 1024, 0, stream>>>(
      (const float*)d_in[2], (const float*)d_in[3], (const float*)d_in[4],
      (const float*)d_in[6], (const float*)d_in[7], (const float*)d_in[8],
      (char*)d_ws);
  icb_main<<<4096, 256, 0, stream>>>(
      (const float*)d_in[0], (const float*)d_in[1],
      (const float*)d_in[5], (const float*)d_in[9],
      (const char*)d_ws, (float*)d_out);
}